// Round 1
// baseline (57139.520 us; speedup 1.0000x reference)
//
#include <hip/hip_runtime.h>
#include <math.h>

namespace {

constexpr int BATCH = 2;
constexpr int H = 1080;
constexpr int W = 1920;
constexpr int HW = H * W;
constexpr int PL = BATCH * HW;          // elements per channel-plane (all batches)
constexpr int NTH = 256;
constexpr int NBLK = (PL + NTH - 1) / NTH;

__device__ __forceinline__ float gamma22(float v) {
    // pow(max(v,0), 1/2.2)
    return v > 0.f ? exp2f(0.45454545454545453f * log2f(v)) : 0.f;
}

// in (GAMMA): x_in layout (B,10,H,W). in (!GAMMA): ws layout [ci][b][y][x].
// out: ws layout [co][b][y][x].
template<int CIN, int COUT, bool GAMMA, bool RELU>
__global__ void __launch_bounds__(NTH) conv3x3_k(
        const float* __restrict__ in, const float* __restrict__ wgt,
        const float* __restrict__ bias, float* __restrict__ out)
{
    __shared__ float sw[COUT * CIN * 9];
    for (int i = threadIdx.x; i < COUT * CIN * 9; i += NTH) sw[i] = wgt[i];
    __syncthreads();

    int idx = blockIdx.x * NTH + threadIdx.x;
    if (idx >= PL) return;
    int x = idx % W;
    int y = (idx / W) % H;
    int b = idx / HW;

    float acc[COUT];
#pragma unroll
    for (int co = 0; co < COUT; ++co) acc[co] = bias[co];

#pragma unroll
    for (int ci = 0; ci < CIN; ++ci) {
#pragma unroll
        for (int ky = 0; ky < 3; ++ky) {
            int yy = y + ky - 1;
#pragma unroll
            for (int kx = 0; kx < 3; ++kx) {
                int xx = x + kx - 1;
                float v = 0.f;
                if (yy >= 0 && yy < H && xx >= 0 && xx < W) {
                    if (GAMMA) {
                        if (ci < 3) {
                            float a  = in[((size_t)b * 10 + ci) * HW + yy * W + xx];
                            float al = in[((size_t)b * 10 + ci + 3) * HW + yy * W + xx];
                            v = gamma22(a * al);
                        } else {
                            v = in[((size_t)b * 10 + ci) * HW + yy * W + xx];
                        }
                    } else {
                        v = in[(size_t)ci * PL + (size_t)b * HW + yy * W + xx];
                    }
                }
#pragma unroll
                for (int co = 0; co < COUT; ++co)
                    acc[co] = fmaf(v, sw[(co * CIN + ci) * 9 + ky * 3 + kx], acc[co]);
            }
        }
    }

#pragma unroll
    for (int co = 0; co < COUT; ++co) {
        float r = RELU ? fmaxf(acc[co], 0.f) : acc[co];
        out[(size_t)co * PL + idx] = r;
    }
}

// conv3 (14->12) + guide=exp(out[0:6]) + alpha=softmax(out[6:12]) fused.
// ga layout: planes 0..5 guide, 6..11 alpha, each [b][y][x].
__global__ void __launch_bounds__(NTH) conv_head_k(
        const float* __restrict__ in, const float* __restrict__ wgt,
        const float* __restrict__ bias, float* __restrict__ ga)
{
    constexpr int CIN = 14, COUT = 12;
    __shared__ float sw[COUT * CIN * 9];
    for (int i = threadIdx.x; i < COUT * CIN * 9; i += NTH) sw[i] = wgt[i];
    __syncthreads();

    int idx = blockIdx.x * NTH + threadIdx.x;
    if (idx >= PL) return;
    int x = idx % W;
    int y = (idx / W) % H;
    int b = idx / HW;

    float acc[COUT];
#pragma unroll
    for (int co = 0; co < COUT; ++co) acc[co] = bias[co];

#pragma unroll
    for (int ci = 0; ci < CIN; ++ci) {
#pragma unroll
        for (int ky = 0; ky < 3; ++ky) {
            int yy = y + ky - 1;
#pragma unroll
            for (int kx = 0; kx < 3; ++kx) {
                int xx = x + kx - 1;
                float v = 0.f;
                if (yy >= 0 && yy < H && xx >= 0 && xx < W)
                    v = in[(size_t)ci * PL + (size_t)b * HW + yy * W + xx];
#pragma unroll
                for (int co = 0; co < COUT; ++co)
                    acc[co] = fmaf(v, sw[(co * CIN + ci) * 9 + ky * 3 + kx], acc[co]);
            }
        }
    }

    // guide
#pragma unroll
    for (int c = 0; c < 6; ++c)
        ga[(size_t)c * PL + idx] = expf(acc[c]);
    // softmax over channels 6..11
    float m = acc[6];
#pragma unroll
    for (int c = 7; c < 12; ++c) m = fmaxf(m, acc[c]);
    float e[6]; float s = 0.f;
#pragma unroll
    for (int c = 0; c < 6; ++c) { e[c] = expf(acc[6 + c] - m); s += e[c]; }
    float inv = 1.f / s;
#pragma unroll
    for (int c = 0; c < 6; ++c)
        ga[(size_t)(6 + c) * PL + idx] = e[c] * inv;
}

// Horizontal box pass for scale gi: tmp[0]=sum g, tmp[1..3]=sum g*irr_c
template<int K>
__global__ void __launch_bounds__(NTH) box_h_k(
        const float* __restrict__ ga, int gi, const float* __restrict__ xin,
        float* __restrict__ tmp)
{
    int idx = blockIdx.x * NTH + threadIdx.x;
    if (idx >= PL) return;
    int x = idx % W;
    int y = (idx / W) % H;
    int b = idx / HW;
    constexpr int R = (K - 1) / 2;

    const float* gp = ga + (size_t)gi * PL + (size_t)b * HW + (size_t)y * W;
    const float* i0 = xin + ((size_t)b * 10 + 0) * HW + (size_t)y * W;
    const float* i1 = xin + ((size_t)b * 10 + 1) * HW + (size_t)y * W;
    const float* i2 = xin + ((size_t)b * 10 + 2) * HW + (size_t)y * W;

    float s0 = 0.f, s1 = 0.f, s2 = 0.f, s3 = 0.f;
#pragma unroll
    for (int dx = -R; dx <= R; ++dx) {
        int xx = x + dx;
        if (xx < 0 || xx >= W) continue;
        float gv = gp[xx];
        s0 += gv;
        s1 += gv * i0[xx];
        s2 += gv * i1[xx];
        s3 += gv * i2[xx];
    }
    tmp[idx] = s0;
    tmp[(size_t)PL + idx] = s1;
    tmp[(size_t)2 * PL + idx] = s2;
    tmp[(size_t)3 * PL + idx] = s3;
}

// Vertical box pass + accumulate alpha * num/wsum. LAST: multiply by alb, write d_out.
template<int K, bool FIRST, bool LAST>
__global__ void __launch_bounds__(NTH) box_v_k(
        const float* __restrict__ tmp, const float* __restrict__ ga, int ai,
        float* __restrict__ acc, const float* __restrict__ xin,
        float* __restrict__ outp)
{
    int idx = blockIdx.x * NTH + threadIdx.x;
    if (idx >= PL) return;
    int x = idx % W;
    int y = (idx / W) % H;
    int b = idx / HW;
    constexpr int R = (K - 1) / 2;

    float s0 = 0.f, s1 = 0.f, s2 = 0.f, s3 = 0.f;
#pragma unroll
    for (int dy = -R; dy <= R; ++dy) {
        int yy = y + dy;
        if (yy < 0 || yy >= H) continue;
        size_t j = (size_t)b * HW + (size_t)yy * W + x;
        s0 += tmp[j];
        s1 += tmp[(size_t)PL + j];
        s2 += tmp[(size_t)2 * PL + j];
        s3 += tmp[(size_t)3 * PL + j];
    }

    float al = ga[(size_t)(6 + ai) * PL + idx];   // alpha_i
    float rw = al / s0;                            // alpha_i / wsum
    float t0 = s1 * rw, t1 = s2 * rw, t2 = s3 * rw;

    if (!FIRST) {
        t0 += acc[idx];
        t1 += acc[(size_t)PL + idx];
        t2 += acc[(size_t)2 * PL + idx];
    }
    if (LAST) {
        size_t p = (size_t)b * 10 * HW + (size_t)y * W + x;
        float a0 = xin[p + (size_t)3 * HW];
        float a1 = xin[p + (size_t)4 * HW];
        float a2 = xin[p + (size_t)5 * HW];
        size_t o = (size_t)b * 3 * HW + (size_t)y * W + x;
        outp[o] = t0 * a0;
        outp[o + HW] = t1 * a1;
        outp[o + (size_t)2 * HW] = t2 * a2;
    } else {
        acc[idx] = t0;
        acc[(size_t)PL + idx] = t1;
        acc[(size_t)2 * PL + idx] = t2;
    }
}

} // namespace

extern "C" void kernel_launch(void* const* d_in, const int* in_sizes, int n_in,
                              void* d_out, int out_size, void* d_ws, size_t ws_size,
                              hipStream_t stream)
{
    const float* xin = (const float*)d_in[0];
    const float* W1p = (const float*)d_in[1];
    const float* b1p = (const float*)d_in[2];
    const float* W2p = (const float*)d_in[3];
    const float* b2p = (const float*)d_in[4];
    const float* W3p = (const float*)d_in[5];
    const float* b3p = (const float*)d_in[6];
    float* outp = (float*)d_out;
    float* ws = (float*)d_ws;

    // ws layout (28 planes of PL floats, ~465 MB):
    //   h1 : planes  0..13   (dead after conv2)
    //   h2 : planes 14..27   (dead after conv_head)
    //   ga : planes  0..11   (reuses h1 region)
    //   tmp: planes 14..17   (reuses h2 region)
    //   acc: planes 18..20   (reuses h2 region)
    float* h1  = ws;
    float* h2  = ws + (size_t)14 * PL;
    float* ga  = ws;
    float* tmp = ws + (size_t)14 * PL;
    float* acc = ws + (size_t)18 * PL;

    dim3 grid(NBLK), blk(NTH);

    conv3x3_k<10, 14, true,  true ><<<grid, blk, 0, stream>>>(xin, W1p, b1p, h1);
    conv3x3_k<14, 14, false, true ><<<grid, blk, 0, stream>>>(h1,  W2p, b2p, h2);
    conv_head_k<<<grid, blk, 0, stream>>>(h2, W3p, b3p, ga);

    box_h_k<3 ><<<grid, blk, 0, stream>>>(ga, 0, xin, tmp);
    box_v_k<3,  true,  false><<<grid, blk, 0, stream>>>(tmp, ga, 0, acc, xin, outp);
    box_h_k<5 ><<<grid, blk, 0, stream>>>(ga, 1, xin, tmp);
    box_v_k<5,  false, false><<<grid, blk, 0, stream>>>(tmp, ga, 1, acc, xin, outp);
    box_h_k<7 ><<<grid, blk, 0, stream>>>(ga, 2, xin, tmp);
    box_v_k<7,  false, false><<<grid, blk, 0, stream>>>(tmp, ga, 2, acc, xin, outp);
    box_h_k<9 ><<<grid, blk, 0, stream>>>(ga, 3, xin, tmp);
    box_v_k<9,  false, false><<<grid, blk, 0, stream>>>(tmp, ga, 3, acc, xin, outp);
    box_h_k<11><<<grid, blk, 0, stream>>>(ga, 4, xin, tmp);
    box_v_k<11, false, false><<<grid, blk, 0, stream>>>(tmp, ga, 4, acc, xin, outp);
    box_h_k<13><<<grid, blk, 0, stream>>>(ga, 5, xin, tmp);
    box_v_k<13, false, true ><<<grid, blk, 0, stream>>>(tmp, ga, 5, acc, xin, outp);
}

// Round 2
// 1396.056 us; speedup vs baseline: 40.9293x; 40.9293x over previous
//
#include <hip/hip_runtime.h>
#include <math.h>

namespace {

constexpr int BATCH = 2;
constexpr int H = 1080;
constexpr int W = 1920;
constexpr int HW = H * W;
constexpr int PL = BATCH * HW;          // elements per channel-plane (all batches)
constexpr int NTH = 256;
constexpr int NBLK = (PL + NTH - 1) / NTH;

// conv tile geometry: 64x4 outputs per 256-thread block, 66x6 halo tile in LDS
constexpr int TX = 64;
constexpr int TY = 4;
constexpr int TW = TX + 2;
constexpr int TH = TY + 2;
constexpr int TN = TW * TH;             // 396

__device__ __forceinline__ float gamma22(float v) {
    // pow(max(v,0), 1/2.2)
    return v > 0.f ? exp2f(0.45454545454545453f * log2f(v)) : 0.f;
}

// Fused 3x3 conv over small channel counts.
// GAMMA: input is x_in (B,10,H,W); channels 0..2 are gamma(irr*alb), 3..CIN-1 raw.
// !GAMMA: input is ws layout [ci][b][y][x].
// HEAD:  epilogue writes guide=exp(acc[0:6]) and alpha=softmax(acc[6:12]) to out
//        (planes 0..5 guide, 6..11 alpha). Else writes COUT planes (opt. ReLU).
template<int CIN, int COUT, bool GAMMA, bool RELU, bool HEAD>
__global__ __launch_bounds__(NTH) void conv_tile_k(
        const float* __restrict__ in, const float* __restrict__ wgt,
        const float* __restrict__ bias, float* __restrict__ out)
{
    __shared__ float tile[TN];

    const int tx = threadIdx.x & 63;
    const int ty = threadIdx.x >> 6;
    const int x0 = blockIdx.x * TX;
    const int y0 = blockIdx.y * TY;
    const int b  = blockIdx.z;

    float acc[COUT];
#pragma unroll
    for (int co = 0; co < COUT; ++co) acc[co] = bias[co];

    // ci loop deliberately NOT unrolled: full unroll caused catastrophic
    // register spill (256 VGPR cap, 5.4KB scratch/thread, 35GB HBM traffic).
    for (int ci = 0; ci < CIN; ++ci) {
        __syncthreads();   // previous iteration's tile reads must finish
        for (int i = threadIdx.x; i < TN; i += NTH) {
            int r = i / TW, c = i - r * TW;
            int gy = y0 + r - 1, gx = x0 + c - 1;
            float v = 0.f;
            if (gy >= 0 && gy < H && gx >= 0 && gx < W) {
                if (GAMMA) {
                    if (ci < 3) {
                        float a  = in[((size_t)b * 10 + ci) * HW + (size_t)gy * W + gx];
                        float al = in[((size_t)b * 10 + ci + 3) * HW + (size_t)gy * W + gx];
                        v = gamma22(a * al);
                    } else {
                        v = in[((size_t)b * 10 + ci) * HW + (size_t)gy * W + gx];
                    }
                } else {
                    v = in[(size_t)ci * PL + (size_t)b * HW + (size_t)gy * W + gx];
                }
            }
            tile[i] = v;
        }
        __syncthreads();

        // 9 taps from LDS; weights via wave-uniform global reads -> s_load/SGPR
#pragma unroll
        for (int ky = 0; ky < 3; ++ky) {
#pragma unroll
            for (int kx = 0; kx < 3; ++kx) {
                float v = tile[(ty + ky) * TW + tx + kx];
#pragma unroll
                for (int co = 0; co < COUT; ++co)
                    acc[co] = fmaf(v, wgt[(co * CIN + ci) * 9 + ky * 3 + kx], acc[co]);
            }
        }
    }

    const int x = x0 + tx, y = y0 + ty;
    const size_t oidx = (size_t)b * HW + (size_t)y * W + x;

    if (HEAD) {
        // guide = exp(acc[0:6])
#pragma unroll
        for (int c = 0; c < 6; ++c)
            out[(size_t)c * PL + oidx] = expf(acc[c]);
        // alpha = softmax(acc[6:12])
        float m = acc[6];
#pragma unroll
        for (int c = 7; c < 12; ++c) m = fmaxf(m, acc[c]);
        float e[6]; float s = 0.f;
#pragma unroll
        for (int c = 0; c < 6; ++c) { e[c] = expf(acc[6 + c] - m); s += e[c]; }
        float inv = 1.f / s;
#pragma unroll
        for (int c = 0; c < 6; ++c)
            out[(size_t)(6 + c) * PL + oidx] = e[c] * inv;
    } else {
#pragma unroll
        for (int co = 0; co < COUT; ++co) {
            float r = RELU ? fmaxf(acc[co], 0.f) : acc[co];
            out[(size_t)co * PL + oidx] = r;
        }
    }
}

// Horizontal box pass for scale gi: tmp[0]=sum g, tmp[1..3]=sum g*irr_c
template<int K>
__global__ void __launch_bounds__(NTH) box_h_k(
        const float* __restrict__ ga, int gi, const float* __restrict__ xin,
        float* __restrict__ tmp)
{
    int idx = blockIdx.x * NTH + threadIdx.x;
    if (idx >= PL) return;
    int x = idx % W;
    int y = (idx / W) % H;
    int b = idx / HW;
    constexpr int R = (K - 1) / 2;

    const float* gp = ga + (size_t)gi * PL + (size_t)b * HW + (size_t)y * W;
    const float* i0 = xin + ((size_t)b * 10 + 0) * HW + (size_t)y * W;
    const float* i1 = xin + ((size_t)b * 10 + 1) * HW + (size_t)y * W;
    const float* i2 = xin + ((size_t)b * 10 + 2) * HW + (size_t)y * W;

    float s0 = 0.f, s1 = 0.f, s2 = 0.f, s3 = 0.f;
#pragma unroll
    for (int dx = -R; dx <= R; ++dx) {
        int xx = x + dx;
        if (xx < 0 || xx >= W) continue;
        float gv = gp[xx];
        s0 += gv;
        s1 += gv * i0[xx];
        s2 += gv * i1[xx];
        s3 += gv * i2[xx];
    }
    tmp[idx] = s0;
    tmp[(size_t)PL + idx] = s1;
    tmp[(size_t)2 * PL + idx] = s2;
    tmp[(size_t)3 * PL + idx] = s3;
}

// Vertical box pass + accumulate alpha * num/wsum. LAST: multiply by alb, write d_out.
template<int K, bool FIRST, bool LAST>
__global__ void __launch_bounds__(NTH) box_v_k(
        const float* __restrict__ tmp, const float* __restrict__ ga, int ai,
        float* __restrict__ acc, const float* __restrict__ xin,
        float* __restrict__ outp)
{
    int idx = blockIdx.x * NTH + threadIdx.x;
    if (idx >= PL) return;
    int x = idx % W;
    int y = (idx / W) % H;
    int b = idx / HW;
    constexpr int R = (K - 1) / 2;

    float s0 = 0.f, s1 = 0.f, s2 = 0.f, s3 = 0.f;
#pragma unroll
    for (int dy = -R; dy <= R; ++dy) {
        int yy = y + dy;
        if (yy < 0 || yy >= H) continue;
        size_t j = (size_t)b * HW + (size_t)yy * W + x;
        s0 += tmp[j];
        s1 += tmp[(size_t)PL + j];
        s2 += tmp[(size_t)2 * PL + j];
        s3 += tmp[(size_t)3 * PL + j];
    }

    float al = ga[(size_t)(6 + ai) * PL + idx];   // alpha_i
    float rw = al / s0;                            // alpha_i / wsum
    float t0 = s1 * rw, t1 = s2 * rw, t2 = s3 * rw;

    if (!FIRST) {
        t0 += acc[idx];
        t1 += acc[(size_t)PL + idx];
        t2 += acc[(size_t)2 * PL + idx];
    }
    if (LAST) {
        size_t p = (size_t)b * 10 * HW + (size_t)y * W + x;
        float a0 = xin[p + (size_t)3 * HW];
        float a1 = xin[p + (size_t)4 * HW];
        float a2 = xin[p + (size_t)5 * HW];
        size_t o = (size_t)b * 3 * HW + (size_t)y * W + x;
        outp[o] = t0 * a0;
        outp[o + HW] = t1 * a1;
        outp[o + (size_t)2 * HW] = t2 * a2;
    } else {
        acc[idx] = t0;
        acc[(size_t)PL + idx] = t1;
        acc[(size_t)2 * PL + idx] = t2;
    }
}

} // namespace

extern "C" void kernel_launch(void* const* d_in, const int* in_sizes, int n_in,
                              void* d_out, int out_size, void* d_ws, size_t ws_size,
                              hipStream_t stream)
{
    const float* xin = (const float*)d_in[0];
    const float* W1p = (const float*)d_in[1];
    const float* b1p = (const float*)d_in[2];
    const float* W2p = (const float*)d_in[3];
    const float* b2p = (const float*)d_in[4];
    const float* W3p = (const float*)d_in[5];
    const float* b3p = (const float*)d_in[6];
    float* outp = (float*)d_out;
    float* ws = (float*)d_ws;

    // ws layout (28 planes of PL floats, ~465 MB):
    //   h1 : planes  0..13   (dead after conv2)
    //   h2 : planes 14..27   (dead after conv_head)
    //   ga : planes  0..11   (reuses h1 region)
    //   tmp: planes 14..17   (reuses h2 region)
    //   acc: planes 18..20   (reuses h2 region)
    float* h1  = ws;
    float* h2  = ws + (size_t)14 * PL;
    float* ga  = ws;
    float* tmp = ws + (size_t)14 * PL;
    float* acc = ws + (size_t)18 * PL;

    dim3 cgrid(W / TX, H / TY, BATCH), blk(NTH);
    dim3 grid(NBLK);

    conv_tile_k<10, 14, true,  true,  false><<<cgrid, blk, 0, stream>>>(xin, W1p, b1p, h1);
    conv_tile_k<14, 14, false, true,  false><<<cgrid, blk, 0, stream>>>(h1,  W2p, b2p, h2);
    conv_tile_k<14, 12, false, false, true ><<<cgrid, blk, 0, stream>>>(h2,  W3p, b3p, ga);

    box_h_k<3 ><<<grid, blk, 0, stream>>>(ga, 0, xin, tmp);
    box_v_k<3,  true,  false><<<grid, blk, 0, stream>>>(tmp, ga, 0, acc, xin, outp);
    box_h_k<5 ><<<grid, blk, 0, stream>>>(ga, 1, xin, tmp);
    box_v_k<5,  false, false><<<grid, blk, 0, stream>>>(tmp, ga, 1, acc, xin, outp);
    box_h_k<7 ><<<grid, blk, 0, stream>>>(ga, 2, xin, tmp);
    box_v_k<7,  false, false><<<grid, blk, 0, stream>>>(tmp, ga, 2, acc, xin, outp);
    box_h_k<9 ><<<grid, blk, 0, stream>>>(ga, 3, xin, tmp);
    box_v_k<9,  false, false><<<grid, blk, 0, stream>>>(tmp, ga, 3, acc, xin, outp);
    box_h_k<11><<<grid, blk, 0, stream>>>(ga, 4, xin, tmp);
    box_v_k<11, false, false><<<grid, blk, 0, stream>>>(tmp, ga, 4, acc, xin, outp);
    box_h_k<13><<<grid, blk, 0, stream>>>(ga, 5, xin, tmp);
    box_v_k<13, false, true ><<<grid, blk, 0, stream>>>(tmp, ga, 5, acc, xin, outp);
}

// Round 3
// 1072.664 us; speedup vs baseline: 53.2688x; 1.3015x over previous
//
#include <hip/hip_runtime.h>
#include <math.h>

namespace {

constexpr int BATCH = 2;
constexpr int H = 1080;
constexpr int W = 1920;
constexpr int HW = H * W;
constexpr int PL = BATCH * HW;          // elements per channel-plane (all batches)
constexpr int NTH = 256;
constexpr int NBLK = (PL + NTH - 1) / NTH;

// conv tile: 128x8 outputs per 256-thread block, 4 px per thread along x.
// LDS halo tile 130x10, row stride padded to 132 (16B-aligned float4 reads).
constexpr int BX = 128;
constexpr int BY = 8;
constexpr int LW = 132;                 // padded row stride (cols 0..129 used)
constexpr int LH = 10;
constexpr int LDSN = LW * LH;           // 1320 floats
constexpr int NSTG = (LDSN + NTH - 1) / NTH;   // 6 staging slots/thread

__device__ __forceinline__ float gamma22(float v) {
    return v > 0.f ? exp2f(0.45454545454545453f * log2f(v)) : 0.f;
}

// Fused 3x3 conv, 4 outputs/thread.
// GAMMA: input x_in (B,10,H,W), ch 0..2 = gamma(irr*alb), 3.. raw.
// !GAMMA: input ws planes [ci][b][y][x].
// HEAD: writes guide=exp(acc[0:6]), alpha=softmax(acc[6:12]).
template<int CIN, int COUT, bool GAMMA, bool RELU, bool HEAD>
__global__ __launch_bounds__(NTH) void conv4_k(
        const float* __restrict__ in, const float* __restrict__ wgt,
        const float* __restrict__ bias, float* __restrict__ out)
{
    __shared__ float tile[LDSN];

    const int tx = threadIdx.x & 31;    // 32 groups of 4 px in x
    const int ty = threadIdx.x >> 5;    // 8 rows
    const int x0 = blockIdx.x * BX;
    const int y0 = blockIdx.y * BY;
    const int b  = blockIdx.z;

    float acc[COUT][4];
#pragma unroll
    for (int co = 0; co < COUT; ++co) {
        float bv = bias[co];
#pragma unroll
        for (int p = 0; p < 4; ++p) acc[co][p] = bv;
    }

    float rg[NSTG];

    // stage channel ci's halo tile (130x10) into registers
    auto stage_load = [&](int ci) {
#pragma unroll
        for (int s = 0; s < NSTG; ++s) {
            int i = threadIdx.x + s * NTH;
            float v = 0.f;
            if (i < LDSN) {
                int r = i / LW, c = i - r * LW;
                int gy = y0 + r - 1, gx = x0 + c - 1;
                if (c < 130 && gy >= 0 && gy < H && gx >= 0 && gx < W) {
                    if (GAMMA) {
                        if (ci < 3) {
                            float a  = in[((size_t)b * 10 + ci) * HW + (size_t)gy * W + gx];
                            float al = in[((size_t)b * 10 + ci + 3) * HW + (size_t)gy * W + gx];
                            v = gamma22(a * al);
                        } else {
                            v = in[((size_t)b * 10 + ci) * HW + (size_t)gy * W + gx];
                        }
                    } else {
                        v = in[(size_t)ci * PL + (size_t)b * HW + (size_t)gy * W + gx];
                    }
                }
            }
            rg[s] = v;
        }
    };

    stage_load(0);

    for (int ci = 0; ci < CIN; ++ci) {
        __syncthreads();                 // prior compute done reading tile
#pragma unroll
        for (int s = 0; s < NSTG; ++s) {
            int i = threadIdx.x + s * NTH;
            if (i < LDSN) tile[i] = rg[s];
        }
        __syncthreads();                 // tile ready

        if (ci + 1 < CIN) stage_load(ci + 1);   // T14: issue loads, hide under FMAs

        // read 6-col window per row: aligned float4 + 2 scalars
        float v[3][6];
#pragma unroll
        for (int ky = 0; ky < 3; ++ky) {
            int row = (ty + ky) * LW + tx * 4;
            float4 v4 = *reinterpret_cast<const float4*>(&tile[row]);
            v[ky][0] = v4.x; v[ky][1] = v4.y; v[ky][2] = v4.z; v[ky][3] = v4.w;
            v[ky][4] = tile[row + 4];
            v[ky][5] = tile[row + 5];
        }

#pragma unroll
        for (int ky = 0; ky < 3; ++ky) {
#pragma unroll
            for (int kx = 0; kx < 3; ++kx) {
#pragma unroll
                for (int co = 0; co < COUT; ++co) {
                    float w = wgt[(co * CIN + ci) * 9 + ky * 3 + kx];
#pragma unroll
                    for (int p = 0; p < 4; ++p)
                        acc[co][p] = fmaf(v[ky][p + kx], w, acc[co][p]);
                }
            }
        }
    }

    const int y = y0 + ty;
    const size_t obase = (size_t)b * HW + (size_t)y * W + x0 + tx * 4;

    if (HEAD) {
#pragma unroll
        for (int p = 0; p < 4; ++p) {
            // guide = exp(acc[0:6])
#pragma unroll
            for (int c = 0; c < 6; ++c)
                out[(size_t)c * PL + obase + p] = expf(acc[c][p]);
            float m = acc[6][p];
#pragma unroll
            for (int c = 7; c < 12; ++c) m = fmaxf(m, acc[c][p]);
            float e[6]; float s = 0.f;
#pragma unroll
            for (int c = 0; c < 6; ++c) { e[c] = expf(acc[6 + c][p] - m); s += e[c]; }
            float inv = 1.f / s;
#pragma unroll
            for (int c = 0; c < 6; ++c)
                out[(size_t)(6 + c) * PL + obase + p] = e[c] * inv;
        }
    } else {
#pragma unroll
        for (int co = 0; co < COUT; ++co) {
            float4 r;
            r.x = RELU ? fmaxf(acc[co][0], 0.f) : acc[co][0];
            r.y = RELU ? fmaxf(acc[co][1], 0.f) : acc[co][1];
            r.z = RELU ? fmaxf(acc[co][2], 0.f) : acc[co][2];
            r.w = RELU ? fmaxf(acc[co][3], 0.f) : acc[co][3];
            *reinterpret_cast<float4*>(&out[(size_t)co * PL + obase]) = r;
        }
    }
}

// Horizontal box pass for scale gi: tmp[0]=sum g, tmp[1..3]=sum g*irr_c
template<int K>
__global__ void __launch_bounds__(NTH) box_h_k(
        const float* __restrict__ ga, int gi, const float* __restrict__ xin,
        float* __restrict__ tmp)
{
    int idx = blockIdx.x * NTH + threadIdx.x;
    if (idx >= PL) return;
    int x = idx % W;
    int y = (idx / W) % H;
    int b = idx / HW;
    constexpr int R = (K - 1) / 2;

    const float* gp = ga + (size_t)gi * PL + (size_t)b * HW + (size_t)y * W;
    const float* i0 = xin + ((size_t)b * 10 + 0) * HW + (size_t)y * W;
    const float* i1 = xin + ((size_t)b * 10 + 1) * HW + (size_t)y * W;
    const float* i2 = xin + ((size_t)b * 10 + 2) * HW + (size_t)y * W;

    float s0 = 0.f, s1 = 0.f, s2 = 0.f, s3 = 0.f;
#pragma unroll
    for (int dx = -R; dx <= R; ++dx) {
        int xx = x + dx;
        if (xx < 0 || xx >= W) continue;
        float gv = gp[xx];
        s0 += gv;
        s1 += gv * i0[xx];
        s2 += gv * i1[xx];
        s3 += gv * i2[xx];
    }
    tmp[idx] = s0;
    tmp[(size_t)PL + idx] = s1;
    tmp[(size_t)2 * PL + idx] = s2;
    tmp[(size_t)3 * PL + idx] = s3;
}

// Vertical box pass + accumulate alpha * num/wsum. LAST: multiply by alb, write d_out.
template<int K, bool FIRST, bool LAST>
__global__ void __launch_bounds__(NTH) box_v_k(
        const float* __restrict__ tmp, const float* __restrict__ ga, int ai,
        float* __restrict__ acc, const float* __restrict__ xin,
        float* __restrict__ outp)
{
    int idx = blockIdx.x * NTH + threadIdx.x;
    if (idx >= PL) return;
    int x = idx % W;
    int y = (idx / W) % H;
    int b = idx / HW;
    constexpr int R = (K - 1) / 2;

    float s0 = 0.f, s1 = 0.f, s2 = 0.f, s3 = 0.f;
#pragma unroll
    for (int dy = -R; dy <= R; ++dy) {
        int yy = y + dy;
        if (yy < 0 || yy >= H) continue;
        size_t j = (size_t)b * HW + (size_t)yy * W + x;
        s0 += tmp[j];
        s1 += tmp[(size_t)PL + j];
        s2 += tmp[(size_t)2 * PL + j];
        s3 += tmp[(size_t)3 * PL + j];
    }

    float al = ga[(size_t)(6 + ai) * PL + idx];   // alpha_i
    float rw = al / s0;                            // alpha_i / wsum
    float t0 = s1 * rw, t1 = s2 * rw, t2 = s3 * rw;

    if (!FIRST) {
        t0 += acc[idx];
        t1 += acc[(size_t)PL + idx];
        t2 += acc[(size_t)2 * PL + idx];
    }
    if (LAST) {
        size_t p = (size_t)b * 10 * HW + (size_t)y * W + x;
        float a0 = xin[p + (size_t)3 * HW];
        float a1 = xin[p + (size_t)4 * HW];
        float a2 = xin[p + (size_t)5 * HW];
        size_t o = (size_t)b * 3 * HW + (size_t)y * W + x;
        outp[o] = t0 * a0;
        outp[o + HW] = t1 * a1;
        outp[o + (size_t)2 * HW] = t2 * a2;
    } else {
        acc[idx] = t0;
        acc[(size_t)PL + idx] = t1;
        acc[(size_t)2 * PL + idx] = t2;
    }
}

} // namespace

extern "C" void kernel_launch(void* const* d_in, const int* in_sizes, int n_in,
                              void* d_out, int out_size, void* d_ws, size_t ws_size,
                              hipStream_t stream)
{
    const float* xin = (const float*)d_in[0];
    const float* W1p = (const float*)d_in[1];
    const float* b1p = (const float*)d_in[2];
    const float* W2p = (const float*)d_in[3];
    const float* b2p = (const float*)d_in[4];
    const float* W3p = (const float*)d_in[5];
    const float* b3p = (const float*)d_in[6];
    float* outp = (float*)d_out;
    float* ws = (float*)d_ws;

    // ws layout (28 planes of PL floats):
    //   h1 : planes  0..13 ; h2 : planes 14..27
    //   ga : planes  0..11 (reuses h1) ; tmp: 14..17 ; acc: 18..20
    float* h1  = ws;
    float* h2  = ws + (size_t)14 * PL;
    float* ga  = ws;
    float* tmp = ws + (size_t)14 * PL;
    float* acc = ws + (size_t)18 * PL;

    dim3 cgrid(W / BX, H / BY, BATCH), blk(NTH);
    dim3 grid(NBLK);

    conv4_k<10, 14, true,  true,  false><<<cgrid, blk, 0, stream>>>(xin, W1p, b1p, h1);
    conv4_k<14, 14, false, true,  false><<<cgrid, blk, 0, stream>>>(h1,  W2p, b2p, h2);
    conv4_k<14, 12, false, false, true ><<<cgrid, blk, 0, stream>>>(h2,  W3p, b3p, ga);

    box_h_k<3 ><<<grid, blk, 0, stream>>>(ga, 0, xin, tmp);
    box_v_k<3,  true,  false><<<grid, blk, 0, stream>>>(tmp, ga, 0, acc, xin, outp);
    box_h_k<5 ><<<grid, blk, 0, stream>>>(ga, 1, xin, tmp);
    box_v_k<5,  false, false><<<grid, blk, 0, stream>>>(tmp, ga, 1, acc, xin, outp);
    box_h_k<7 ><<<grid, blk, 0, stream>>>(ga, 2, xin, tmp);
    box_v_k<7,  false, false><<<grid, blk, 0, stream>>>(tmp, ga, 2, acc, xin, outp);
    box_h_k<9 ><<<grid, blk, 0, stream>>>(ga, 3, xin, tmp);
    box_v_k<9,  false, false><<<grid, blk, 0, stream>>>(tmp, ga, 3, acc, xin, outp);
    box_h_k<11><<<grid, blk, 0, stream>>>(ga, 4, xin, tmp);
    box_v_k<11, false, false><<<grid, blk, 0, stream>>>(tmp, ga, 4, acc, xin, outp);
    box_h_k<13><<<grid, blk, 0, stream>>>(ga, 5, xin, tmp);
    box_v_k<13, false, true ><<<grid, blk, 0, stream>>>(tmp, ga, 5, acc, xin, outp);
}